// Round 1
// baseline (716.703 us; speedup 1.0000x reference)
//
#include <hip/hip_runtime.h>
#include <hip/hip_bf16.h>
#include <math.h>

#define D 128
#define H 4
#define TILE_M 32

// ---------------------------------------------------------------------------
// Generic 128-K GEMM:  out[m,n] = (sum_k in[m,k] * W[n,k] + b[n]) * scale
// Block: 256 threads handles TILE_M rows x 128 cols.
// x tile staged in LDS (16KB); W rows read via L1 (64KB W, heavy reuse).
// ---------------------------------------------------------------------------
__global__ __launch_bounds__(256) void gemm128(
    const float* __restrict__ in, const float* __restrict__ W,
    const float* __restrict__ b, float* __restrict__ out,
    float scale, int n)
{
    __shared__ float xs[TILE_M][D];
    const int tid  = threadIdx.x;
    const int row0 = blockIdx.x * TILE_M;

    // cooperative load of the x tile (float4), guarded
    for (int i = tid; i < TILE_M * D / 4; i += 256) {
        int r = (i * 4) / D;
        if (row0 + r < n) {
            ((float4*)xs)[i] = ((const float4*)(in + (size_t)row0 * D))[i];
        }
    }
    __syncthreads();

    const int col = tid & 127;
    const int rg  = tid >> 7;            // 0 or 1: which half of the row tile
    float acc[TILE_M / 2];
#pragma unroll
    for (int j = 0; j < TILE_M / 2; ++j) acc[j] = 0.f;

    const float4* Wrow = (const float4*)(W + (size_t)col * D);
#pragma unroll 8
    for (int k4 = 0; k4 < D / 4; ++k4) {
        float4 w = Wrow[k4];
#pragma unroll
        for (int j = 0; j < TILE_M / 2; ++j) {
            float4 xv = *((const float4*)(&xs[rg * (TILE_M / 2) + j][k4 * 4]));
            acc[j] += w.x * xv.x + w.y * xv.y + w.z * xv.z + w.w * xv.w;
        }
    }

    const float bias = b[col];
#pragma unroll
    for (int j = 0; j < TILE_M / 2; ++j) {
        int m = row0 + rg * (TILE_M / 2) + j;
        if (m < n) out[(size_t)m * D + col] = (acc[j] + bias) * scale;
    }
}

// ---------------------------------------------------------------------------
// row_start[i] = first edge index e with row[e] >= i  (row is sorted)
// ---------------------------------------------------------------------------
__global__ void build_row_start(const int* __restrict__ row,
                                int* __restrict__ row_start, int n, int e)
{
    int i = blockIdx.x * blockDim.x + threadIdx.x;
    if (i > n) return;
    int lo = 0, hi = e;
    while (lo < hi) {
        int mid = (lo + hi) >> 1;
        if (row[mid] < i) lo = mid + 1; else hi = mid;
    }
    row_start[i] = lo;
}

// ---------------------------------------------------------------------------
// SDDMM: s[e,h] = sum_dh q[row[e]][dh*4+h] * k[col[e]][dh*4+h]
// One thread per edge; each float4 covers one dh across all 4 heads.
// ---------------------------------------------------------------------------
__global__ __launch_bounds__(256) void sddmm(
    const float* __restrict__ q, const float* __restrict__ k,
    const int* __restrict__ row, const int* __restrict__ col,
    float* __restrict__ s, int e)
{
    int ed = blockIdx.x * blockDim.x + threadIdx.x;
    if (ed >= e) return;
    const float4* qr = (const float4*)(q + (size_t)row[ed] * D);
    const float4* kr = (const float4*)(k + (size_t)col[ed] * D);
    float a0 = 0.f, a1 = 0.f, a2 = 0.f, a3 = 0.f;
#pragma unroll
    for (int j = 0; j < D / 4; ++j) {
        float4 qv = qr[j];
        float4 kv = kr[j];
        a0 += qv.x * kv.x;
        a1 += qv.y * kv.y;
        a2 += qv.z * kv.z;
        a3 += qv.w * kv.w;
    }
    ((float4*)(s + (size_t)ed * H))[0] = make_float4(a0, a1, a2, a3);
}

// ---------------------------------------------------------------------------
// Segment softmax (in place on s): one thread per (node, head).
// ---------------------------------------------------------------------------
__global__ __launch_bounds__(256) void softmax_edges(
    const int* __restrict__ row_start, float* __restrict__ s, int n)
{
    int t = blockIdx.x * blockDim.x + threadIdx.x;
    if (t >= n * H) return;
    int i = t >> 2, h = t & 3;
    int e0 = row_start[i], e1 = row_start[i + 1];
    if (e0 >= e1) return;
    float m = -INFINITY;
    for (int e = e0; e < e1; ++e) m = fmaxf(m, s[(size_t)e * H + h]);
    float z = 0.f;
    for (int e = e0; e < e1; ++e) {
        float ex = __expf(s[(size_t)e * H + h] - m);
        s[(size_t)e * H + h] = ex;
        z += ex;
    }
    float rz = 1.f / z;
    for (int e = e0; e < e1; ++e) s[(size_t)e * H + h] *= rz;
}

// ---------------------------------------------------------------------------
// SPMM: y[i,d] = sum_{e in row i} a[e, d%4] * v[col[e], d]
// 2 nodes per 256-thread block; thread d covers one output column.
// ---------------------------------------------------------------------------
__global__ __launch_bounds__(256) void spmm(
    const int* __restrict__ row_start, const float* __restrict__ a,
    const float* __restrict__ v, const int* __restrict__ col,
    float* __restrict__ y, int n)
{
    int node = blockIdx.x * 2 + (threadIdx.x >> 7);
    int d = threadIdx.x & 127;
    if (node >= n) return;
    int e0 = row_start[node], e1 = row_start[node + 1];
    int h = d & 3;
    float acc = 0.f;
    for (int e = e0; e < e1; ++e) {
        acc += a[(size_t)e * H + h] * v[(size_t)col[e] * D + d];
    }
    y[(size_t)node * D + d] = acc;
}

// ---------------------------------------------------------------------------
extern "C" void kernel_launch(void* const* d_in, const int* in_sizes, int n_in,
                              void* d_out, int out_size, void* d_ws, size_t ws_size,
                              hipStream_t stream)
{
    const float* x   = (const float*)d_in[0];
    const int*   row = (const int*)  d_in[1];
    const int*   col = (const int*)  d_in[2];
    const float* Wq  = (const float*)d_in[3];
    const float* bq  = (const float*)d_in[4];
    const float* Wk  = (const float*)d_in[5];
    const float* bk  = (const float*)d_in[6];
    const float* Wv  = (const float*)d_in[7];
    const float* bv  = (const float*)d_in[8];
    const float* Wo  = (const float*)d_in[9];
    const float* bo  = (const float*)d_in[10];
    float* out = (float*)d_out;

    const int n = in_sizes[0] / D;   // 100000
    const int e = in_sizes[1];       // 800000
    const size_t ND = (size_t)n * D;

    float* ws = (float*)d_ws;
    float* q  = ws;
    float* k  = ws + ND;
    float* v  = ws + 2 * ND;
    float* y  = ws + 3 * ND;
    float* s  = ws + 4 * ND;                    // E*H floats
    int*   row_start = (int*)(ws + 4 * ND + (size_t)e * H);

    const int gemm_grid = (n + TILE_M - 1) / TILE_M;

    // Projections (q scaled by 1/sqrt(H) = 0.5 per the reference quirk)
    gemm128<<<gemm_grid, 256, 0, stream>>>(x, Wq, bq, q, 0.5f, n);
    gemm128<<<gemm_grid, 256, 0, stream>>>(x, Wk, bk, k, 1.0f, n);
    gemm128<<<gemm_grid, 256, 0, stream>>>(x, Wv, bv, v, 1.0f, n);

    build_row_start<<<(n + 1 + 255) / 256, 256, 0, stream>>>(row, row_start, n, e);

    sddmm<<<(e + 255) / 256, 256, 0, stream>>>(q, k, row, col, s, e);

    softmax_edges<<<(n * H + 255) / 256, 256, 0, stream>>>(row_start, s, n);

    spmm<<<(n + 1) / 2, 256, 0, stream>>>(row_start, s, v, col, y, n);

    // Output projection
    gemm128<<<gemm_grid, 256, 0, stream>>>(y, Wo, bo, out, 1.0f, n);
}

// Round 2
// 616.213 us; speedup vs baseline: 1.1631x; 1.1631x over previous
//
#include <hip/hip_runtime.h>
#include <hip/hip_bf16.h>
#include <math.h>

#define D 128
#define H 4

// ===========================================================================
// Register-tiled fp32 GEMM:  out[m,n] = (sum_k in[m,k]*W[n,k] + b[n]) * scale
// Block 256 threads -> 128x128 output tile, 8x8 accumulators per thread.
// K staged in chunks of 32 (A and W both transposed into LDS as [k][m]/[k][n]).
// ===========================================================================
#define GM 128
#define GN 128
#define KC 32

__global__ __launch_bounds__(256) void gemm128(
    const float* __restrict__ in, const float* __restrict__ W,
    const float* __restrict__ b, float* __restrict__ out,
    float scale, int n)
{
    __shared__ float as[KC][GM + 4];
    __shared__ float ws[KC][GN + 4];

    const int tid = threadIdx.x;
    const int tm  = (tid >> 4) * 8;   // row offset of this thread's 8x8 tile
    const int tn  = (tid & 15) * 8;   // col offset
    const int row0 = blockIdx.x * GM;

    float acc[8][8];
#pragma unroll
    for (int i = 0; i < 8; ++i)
#pragma unroll
        for (int j = 0; j < 8; ++j) acc[i][j] = 0.f;

    for (int kc = 0; kc < D; kc += KC) {
        // ---- stage A chunk (transpose to as[k][m]); clamp OOB rows ----
#pragma unroll
        for (int p = 0; p < 4; ++p) {
            int idx = p * 256 + tid;
            int m   = idx >> 3;
            int k4  = (idx & 7) * 4;
            int r   = row0 + m; if (r > n - 1) r = n - 1;
            float4 vA = *(const float4*)(in + (size_t)r * D + kc + k4);
            as[k4 + 0][m] = vA.x; as[k4 + 1][m] = vA.y;
            as[k4 + 2][m] = vA.z; as[k4 + 3][m] = vA.w;
        }
        // ---- stage W chunk (transpose to ws[k][nn]) ----
#pragma unroll
        for (int p = 0; p < 4; ++p) {
            int idx = p * 256 + tid;
            int nn  = idx >> 3;
            int k4  = (idx & 7) * 4;
            float4 vW = *(const float4*)(W + (size_t)nn * D + kc + k4);
            ws[k4 + 0][nn] = vW.x; ws[k4 + 1][nn] = vW.y;
            ws[k4 + 2][nn] = vW.z; ws[k4 + 3][nn] = vW.w;
        }
        __syncthreads();

#pragma unroll 4
        for (int k = 0; k < KC; ++k) {
            float4 a0 = *(const float4*)&as[k][tm];
            float4 a1 = *(const float4*)&as[k][tm + 4];
            float4 w0 = *(const float4*)&ws[k][tn];
            float4 w1 = *(const float4*)&ws[k][tn + 4];
            float av[8] = {a0.x, a0.y, a0.z, a0.w, a1.x, a1.y, a1.z, a1.w};
            float wv[8] = {w0.x, w0.y, w0.z, w0.w, w1.x, w1.y, w1.z, w1.w};
#pragma unroll
            for (int i = 0; i < 8; ++i)
#pragma unroll
                for (int j = 0; j < 8; ++j) acc[i][j] += av[i] * wv[j];
        }
        __syncthreads();
    }

    // ---- epilogue: bias, scale, guarded store ----
    float bias[8];
#pragma unroll
    for (int j = 0; j < 8; ++j) bias[j] = b[tn + j];
#pragma unroll
    for (int i = 0; i < 8; ++i) {
        int r = row0 + tm + i;
        if (r < n) {
            float4 o0, o1;
            o0.x = (acc[i][0] + bias[0]) * scale;
            o0.y = (acc[i][1] + bias[1]) * scale;
            o0.z = (acc[i][2] + bias[2]) * scale;
            o0.w = (acc[i][3] + bias[3]) * scale;
            o1.x = (acc[i][4] + bias[4]) * scale;
            o1.y = (acc[i][5] + bias[5]) * scale;
            o1.z = (acc[i][6] + bias[6]) * scale;
            o1.w = (acc[i][7] + bias[7]) * scale;
            *(float4*)(out + (size_t)r * D + tn)     = o0;
            *(float4*)(out + (size_t)r * D + tn + 4) = o1;
        }
    }
}

// ---------------------------------------------------------------------------
// row_start[i] = first edge index e with row[e] >= i  (row is sorted)
// ---------------------------------------------------------------------------
__global__ void build_row_start(const int* __restrict__ row,
                                int* __restrict__ row_start, int n, int e)
{
    int i = blockIdx.x * blockDim.x + threadIdx.x;
    if (i > n) return;
    int lo = 0, hi = e;
    while (lo < hi) {
        int mid = (lo + hi) >> 1;
        if (row[mid] < i) lo = mid + 1; else hi = mid;
    }
    row_start[i] = lo;
}

// ---------------------------------------------------------------------------
// SDDMM: s[e,h] = sum_dh q[row[e]][dh*4+h] * k[col[e]][dh*4+h]
// ---------------------------------------------------------------------------
__global__ __launch_bounds__(256) void sddmm(
    const float* __restrict__ q, const float* __restrict__ k,
    const int* __restrict__ row, const int* __restrict__ col,
    float* __restrict__ s, int e)
{
    int ed = blockIdx.x * blockDim.x + threadIdx.x;
    if (ed >= e) return;
    const float4* qr = (const float4*)(q + (size_t)row[ed] * D);
    const float4* kr = (const float4*)(k + (size_t)col[ed] * D);
    float a0 = 0.f, a1 = 0.f, a2 = 0.f, a3 = 0.f;
#pragma unroll
    for (int j = 0; j < D / 4; ++j) {
        float4 qv = qr[j];
        float4 kv = kr[j];
        a0 += qv.x * kv.x;
        a1 += qv.y * kv.y;
        a2 += qv.z * kv.z;
        a3 += qv.w * kv.w;
    }
    ((float4*)(s + (size_t)ed * H))[0] = make_float4(a0, a1, a2, a3);
}

// ---------------------------------------------------------------------------
// Fused segment-softmax + SPMM.
// 2 nodes per 256-thread block (128 threads = columns per node).
// Edge metadata (col, normalized attention) staged in LDS (fast path deg<=64),
// then unroll-by-4 accumulation so v-row gathers issue independently.
// ---------------------------------------------------------------------------
#define MAXDEG 64

__global__ __launch_bounds__(256) void spmm_softmax(
    const int* __restrict__ row_start, const float* __restrict__ s,
    const float* __restrict__ v, const int* __restrict__ col,
    float* __restrict__ y, int n)
{
    __shared__ int   cm[2][MAXDEG];
    __shared__ float am[2][MAXDEG][H];
    __shared__ float mmv[2][H], zrv[2][H];

    const int g  = threadIdx.x >> 7;   // node group within block
    const int lt = threadIdx.x & 127;  // lane within group
    const int node = blockIdx.x * 2 + g;
    const bool valid = node < n;

    int e0 = 0, deg = 0;
    if (valid) {
        e0  = row_start[node];
        deg = row_start[node + 1] - e0;
    }
    const int dl = deg < MAXDEG ? deg : MAXDEG;

    // stage col[] for this node
    for (int i = lt; i < dl; i += 128) cm[g][i] = col[e0 + i];

    // per-head softmax stats + normalized weights (threads 0..3 of group)
    if (valid && lt < H) {
        const int h = lt;
        float m = -INFINITY;
        for (int e = 0; e < deg; ++e)
            m = fmaxf(m, s[(size_t)(e0 + e) * H + h]);
        float z = 0.f;
        for (int e = 0; e < deg; ++e)
            z += __expf(s[(size_t)(e0 + e) * H + h] - m);
        float rz = 1.f / z;
        for (int e = 0; e < dl; ++e)
            am[g][e][h] = __expf(s[(size_t)(e0 + e) * H + h] - m) * rz;
        mmv[g][h] = m; zrv[g][h] = rz;
    }
    __syncthreads();
    if (!valid) return;

    const int d = lt;
    const int h = d & 3;
    float acc = 0.f;

    int e = 0;
    for (; e + 4 <= dl; e += 4) {
        int c0 = cm[g][e], c1 = cm[g][e + 1], c2 = cm[g][e + 2], c3 = cm[g][e + 3];
        float a0 = am[g][e][h], a1 = am[g][e + 1][h];
        float a2 = am[g][e + 2][h], a3 = am[g][e + 3][h];
        float v0 = v[(size_t)c0 * D + d];
        float v1 = v[(size_t)c1 * D + d];
        float v2 = v[(size_t)c2 * D + d];
        float v3 = v[(size_t)c3 * D + d];
        acc += a0 * v0 + a1 * v1 + a2 * v2 + a3 * v3;
    }
    for (; e < dl; ++e)
        acc += am[g][e][h] * v[(size_t)cm[g][e] * D + d];

    // rare overflow path (deg > MAXDEG): recompute a on the fly
    if (deg > MAXDEG) {
        float m = mmv[g][h], rz = zrv[g][h];
        for (int e2 = MAXDEG; e2 < deg; ++e2) {
            float a = __expf(s[(size_t)(e0 + e2) * H + h] - m) * rz;
            acc += a * v[(size_t)col[e0 + e2] * D + d];
        }
    }

    y[(size_t)node * D + d] = acc;
}

// ---------------------------------------------------------------------------
extern "C" void kernel_launch(void* const* d_in, const int* in_sizes, int n_in,
                              void* d_out, int out_size, void* d_ws, size_t ws_size,
                              hipStream_t stream)
{
    const float* x   = (const float*)d_in[0];
    const int*   row = (const int*)  d_in[1];
    const int*   col = (const int*)  d_in[2];
    const float* Wq  = (const float*)d_in[3];
    const float* bq  = (const float*)d_in[4];
    const float* Wk  = (const float*)d_in[5];
    const float* bk  = (const float*)d_in[6];
    const float* Wv  = (const float*)d_in[7];
    const float* bv  = (const float*)d_in[8];
    const float* Wo  = (const float*)d_in[9];
    const float* bo  = (const float*)d_in[10];
    float* out = (float*)d_out;

    const int n = in_sizes[0] / D;   // 100000
    const int e = in_sizes[1];       // 800000
    const size_t ND = (size_t)n * D;

    float* ws = (float*)d_ws;
    float* q  = ws;
    float* k  = ws + ND;
    float* v  = ws + 2 * ND;
    float* y  = ws + 3 * ND;
    float* s  = ws + 4 * ND;                    // E*H floats
    int*   row_start = (int*)(ws + 4 * ND + (size_t)e * H);

    const int gemm_grid = (n + GM - 1) / GM;

    gemm128<<<gemm_grid, 256, 0, stream>>>(x, Wq, bq, q, 0.5f, n);
    gemm128<<<gemm_grid, 256, 0, stream>>>(x, Wk, bk, k, 1.0f, n);
    gemm128<<<gemm_grid, 256, 0, stream>>>(x, Wv, bv, v, 1.0f, n);

    build_row_start<<<(n + 1 + 255) / 256, 256, 0, stream>>>(row, row_start, n, e);

    sddmm<<<(e + 255) / 256, 256, 0, stream>>>(q, k, row, col, s, e);

    spmm_softmax<<<(n + 1) / 2, 256, 0, stream>>>(row_start, s, v, col, y, n);

    gemm128<<<gemm_grid, 256, 0, stream>>>(y, Wo, bo, out, 1.0f, n);
}

// Round 3
// 446.771 us; speedup vs baseline: 1.6042x; 1.3793x over previous
//
#include <hip/hip_runtime.h>
#include <hip/hip_bf16.h>
#include <math.h>

#define D 128
#define H 4

// ===========================================================================
// Register-tiled fp32 GEMM:  out[m,n] = (sum_k in[m,k]*W[n,k] + b[n]) * scale
// Block 256 threads -> 128x128 output tile, 8x8 accumulators per thread.
// ===========================================================================
#define GM 128
#define GN 128
#define KC 32

__global__ __launch_bounds__(256) void gemm128(
    const float* __restrict__ in, const float* __restrict__ W,
    const float* __restrict__ b, float* __restrict__ out,
    float scale, int n)
{
    __shared__ float as[KC][GM + 4];
    __shared__ float ws[KC][GN + 4];

    const int tid = threadIdx.x;
    const int tm  = (tid >> 4) * 8;
    const int tn  = (tid & 15) * 8;
    const int row0 = blockIdx.x * GM;

    float acc[8][8];
#pragma unroll
    for (int i = 0; i < 8; ++i)
#pragma unroll
        for (int j = 0; j < 8; ++j) acc[i][j] = 0.f;

    for (int kc = 0; kc < D; kc += KC) {
#pragma unroll
        for (int p = 0; p < 4; ++p) {
            int idx = p * 256 + tid;
            int m   = idx >> 3;
            int k4  = (idx & 7) * 4;
            int r   = row0 + m; if (r > n - 1) r = n - 1;
            float4 vA = *(const float4*)(in + (size_t)r * D + kc + k4);
            as[k4 + 0][m] = vA.x; as[k4 + 1][m] = vA.y;
            as[k4 + 2][m] = vA.z; as[k4 + 3][m] = vA.w;
        }
#pragma unroll
        for (int p = 0; p < 4; ++p) {
            int idx = p * 256 + tid;
            int nn  = idx >> 3;
            int k4  = (idx & 7) * 4;
            float4 vW = *(const float4*)(W + (size_t)nn * D + kc + k4);
            ws[k4 + 0][nn] = vW.x; ws[k4 + 1][nn] = vW.y;
            ws[k4 + 2][nn] = vW.z; ws[k4 + 3][nn] = vW.w;
        }
        __syncthreads();

#pragma unroll 4
        for (int k = 0; k < KC; ++k) {
            float4 a0 = *(const float4*)&as[k][tm];
            float4 a1 = *(const float4*)&as[k][tm + 4];
            float4 w0 = *(const float4*)&ws[k][tn];
            float4 w1 = *(const float4*)&ws[k][tn + 4];
            float av[8] = {a0.x, a0.y, a0.z, a0.w, a1.x, a1.y, a1.z, a1.w};
            float wv[8] = {w0.x, w0.y, w0.z, w0.w, w1.x, w1.y, w1.z, w1.w};
#pragma unroll
            for (int i = 0; i < 8; ++i)
#pragma unroll
                for (int j = 0; j < 8; ++j) acc[i][j] += av[i] * wv[j];
        }
        __syncthreads();
    }

    float bias[8];
#pragma unroll
    for (int j = 0; j < 8; ++j) bias[j] = b[tn + j];
#pragma unroll
    for (int i = 0; i < 8; ++i) {
        int r = row0 + tm + i;
        if (r < n) {
            float4 o0, o1;
            o0.x = (acc[i][0] + bias[0]) * scale;
            o0.y = (acc[i][1] + bias[1]) * scale;
            o0.z = (acc[i][2] + bias[2]) * scale;
            o0.w = (acc[i][3] + bias[3]) * scale;
            o1.x = (acc[i][4] + bias[4]) * scale;
            o1.y = (acc[i][5] + bias[5]) * scale;
            o1.z = (acc[i][6] + bias[6]) * scale;
            o1.w = (acc[i][7] + bias[7]) * scale;
            *(float4*)(out + (size_t)r * D + tn)     = o0;
            *(float4*)(out + (size_t)r * D + tn + 4) = o1;
        }
    }
}

// ---------------------------------------------------------------------------
// row_start[i] = first edge index e with row[e] >= i  (row is sorted)
// ---------------------------------------------------------------------------
__global__ void build_row_start(const int* __restrict__ row,
                                int* __restrict__ row_start, int n, int e)
{
    int i = blockIdx.x * blockDim.x + threadIdx.x;
    if (i > n) return;
    int lo = 0, hi = e;
    while (lo < hi) {
        int mid = (lo + hi) >> 1;
        if (row[mid] < i) lo = mid + 1; else hi = mid;
    }
    row_start[i] = lo;
}

// ===========================================================================
// Fused edge phase: SDDMM + segment-softmax + SPMM, one WAVE per node.
//
// Lane l holds feature dims d = l and d = l+64 (both have head h = l&3).
// SDDMM per edge: partial p = q[d0]*k[d0] + q[d1]*k[d1]; butterfly-sum over
// xor masks {4,8,16,32} sums the 16 lanes sharing (lane&3) -> per-head score
// in every lane. Softmax stats kept ONLINE in registers (m,z per lane's head).
// Raw scores parked in per-wave LDS (deg<=64 fast path), normalized in a
// parallel pass, then the SPMM loop gathers v rows (unroll-4 for MLP).
// No __syncthreads anywhere; k-row loads are software-pipelined.
// ===========================================================================
#define MAXDEG 64
#define WPB 4   // waves per block

__global__ __launch_bounds__(WPB * 64) void edge_attn(
    const int* __restrict__ row_start,
    const float* __restrict__ q, const float* __restrict__ k,
    const float* __restrict__ v, const int* __restrict__ col,
    float* __restrict__ y, int n)
{
    __shared__ float ssm[WPB][MAXDEG * H]; // raw scores -> normalized weights
    __shared__ int   cm[WPB][MAXDEG];

    const int wid  = threadIdx.x >> 6;
    const int lane = threadIdx.x & 63;
    const int node = blockIdx.x * WPB + wid;
    if (node >= n) return;                  // wave-uniform, no barriers below

    const int e0  = row_start[node];
    const int deg = row_start[node + 1] - e0;
    const int h   = lane & 3;
    const int dl  = deg < MAXDEG ? deg : MAXDEG;

    // q row for this node (coalesced)
    const float qa = q[(size_t)node * D + lane];
    const float qb = q[(size_t)node * D + lane + 64];

    // stage col[] (coalesced; same wave consumes -> no barrier)
    for (int i = lane; i < dl; i += 64) cm[wid][i] = col[e0 + i];

    // ---- SDDMM + online softmax stats, k-row prefetch pipeline ----
    float m = -INFINITY, z = 0.f;
    float kA = 0.f, kB = 0.f;
    if (deg > 0) {
        int c0 = cm[wid][0];
        kA = k[(size_t)c0 * D + lane];
        kB = k[(size_t)c0 * D + lane + 64];
    }
    for (int e = 0; e < deg; ++e) {
        float cA = kA, cB = kB;
        if (e + 1 < deg) {
            int cn = (e + 1 < MAXDEG) ? cm[wid][e + 1] : col[e0 + e + 1];
            kA = k[(size_t)cn * D + lane];
            kB = k[(size_t)cn * D + lane + 64];
        }
        float p = qa * cA + qb * cB;
        p += __shfl_xor(p, 4);
        p += __shfl_xor(p, 8);
        p += __shfl_xor(p, 16);
        p += __shfl_xor(p, 32);
        // every lane now holds s[e][lane&3]
        if (e < MAXDEG && lane < H) ssm[wid][e * 4 + lane] = p;
        float mn = fmaxf(m, p);
        z = z * __expf(m - mn) + __expf(p - mn);
        m = mn;
    }

    const float rz = 1.f / z;
    // normalize parked scores: slot f = e*4 + h', and (lane + 64t)&3 == lane&3,
    // so this lane's (m, rz) match every slot it touches.
    const int dl4 = dl * 4;
    for (int f = lane; f < dl4; f += 64)
        ssm[wid][f] = __expf(ssm[wid][f] - m) * rz;

    // ---- SPMM: y[node][d] = sum_e a[e][d&3] * v[col[e]][d] ----
    float acc0 = 0.f, acc1 = 0.f;
    int e = 0;
    for (; e + 4 <= dl; e += 4) {
        int c0 = cm[wid][e], c1 = cm[wid][e + 1];
        int c2 = cm[wid][e + 2], c3 = cm[wid][e + 3];
        float a0 = ssm[wid][e * 4 + h],       a1 = ssm[wid][(e + 1) * 4 + h];
        float a2 = ssm[wid][(e + 2) * 4 + h], a3 = ssm[wid][(e + 3) * 4 + h];
        const float* v0 = v + (size_t)c0 * D;
        const float* v1 = v + (size_t)c1 * D;
        const float* v2 = v + (size_t)c2 * D;
        const float* v3 = v + (size_t)c3 * D;
        float p00 = v0[lane],      p10 = v1[lane],      p20 = v2[lane],      p30 = v3[lane];
        float p01 = v0[lane + 64], p11 = v1[lane + 64], p21 = v2[lane + 64], p31 = v3[lane + 64];
        acc0 += a0 * p00 + a1 * p10 + a2 * p20 + a3 * p30;
        acc1 += a0 * p01 + a1 * p11 + a2 * p21 + a3 * p31;
    }
    for (; e < dl; ++e) {
        int c = cm[wid][e];
        float a = ssm[wid][e * 4 + h];
        acc0 += a * v[(size_t)c * D + lane];
        acc1 += a * v[(size_t)c * D + lane + 64];
    }
    // overflow path (deg > MAXDEG): recompute score per edge
    for (int e2 = MAXDEG; e2 < deg; ++e2) {
        int c = col[e0 + e2];
        const float* kr = k + (size_t)c * D;
        float p = qa * kr[lane] + qb * kr[lane + 64];
        p += __shfl_xor(p, 4);
        p += __shfl_xor(p, 8);
        p += __shfl_xor(p, 16);
        p += __shfl_xor(p, 32);
        float a = __expf(p - m) * rz;
        acc0 += a * v[(size_t)c * D + lane];
        acc1 += a * v[(size_t)c * D + lane + 64];
    }

    y[(size_t)node * D + lane]      = acc0;
    y[(size_t)node * D + lane + 64] = acc1;
}

// ---------------------------------------------------------------------------
extern "C" void kernel_launch(void* const* d_in, const int* in_sizes, int n_in,
                              void* d_out, int out_size, void* d_ws, size_t ws_size,
                              hipStream_t stream)
{
    const float* x   = (const float*)d_in[0];
    const int*   row = (const int*)  d_in[1];
    const int*   col = (const int*)  d_in[2];
    const float* Wq  = (const float*)d_in[3];
    const float* bq  = (const float*)d_in[4];
    const float* Wk  = (const float*)d_in[5];
    const float* bk  = (const float*)d_in[6];
    const float* Wv  = (const float*)d_in[7];
    const float* bv  = (const float*)d_in[8];
    const float* Wo  = (const float*)d_in[9];
    const float* bo  = (const float*)d_in[10];
    float* out = (float*)d_out;

    const int n = in_sizes[0] / D;   // 100000
    const int e = in_sizes[1];       // 800000
    const size_t ND = (size_t)n * D;

    float* ws = (float*)d_ws;
    float* q  = ws;
    float* k  = ws + ND;
    float* v  = ws + 2 * ND;
    float* y  = ws + 3 * ND;
    int*   row_start = (int*)(ws + 4 * ND);

    const int gemm_grid = (n + GM - 1) / GM;

    gemm128<<<gemm_grid, 256, 0, stream>>>(x, Wq, bq, q, 0.5f, n);
    gemm128<<<gemm_grid, 256, 0, stream>>>(x, Wk, bk, k, 1.0f, n);
    gemm128<<<gemm_grid, 256, 0, stream>>>(x, Wv, bv, v, 1.0f, n);

    build_row_start<<<(n + 1 + 255) / 256, 256, 0, stream>>>(row, row_start, n, e);

    edge_attn<<<(n + WPB - 1) / WPB, WPB * 64, 0, stream>>>(
        row_start, q, k, v, col, y, n);

    gemm128<<<gemm_grid, 256, 0, stream>>>(y, Wo, bo, out, 1.0f, n);
}